// Round 12
// baseline (159.203 us; speedup 1.0000x reference)
//
#include <hip/hip_runtime.h>
#include <math.h>

// Shapes fixed by setup_inputs(): bs=2, m=16, v=16, L=40320, P=32, beta=1
#define BS 2
#define M 16
#define V 16
#define NROWB 136           // per-batch rows: 16 target + 120 i<j pairs
#define NROWS 272           // BS * NROWB
#define PMASK 32
#define NPB 315             // 128-l chunks per batch (L = NPB*128)
#define NE 8704             // NROWS*PMASK output elements
#define PBSTRIDE 8704       // floats per pb slot in partial (2*136*32)
#define SPLIT 15            // k3a pb-groups
#define QPB 21              // pb per group (315 = 15*21)

typedef __attribute__((ext_vector_type(8))) short bf16x8;
typedef __attribute__((ext_vector_type(4))) float f32x4;
typedef __attribute__((ext_vector_type(4))) unsigned int u32x4;

// counted vmem wait (T4): N = outstanding global_load_lds instrs to LEAVE
#define VMW(n) asm volatile("s_waitcnt vmcnt(" #n ")" ::: "memory")

static __device__ __forceinline__ unsigned short f2bf(float x) {
    unsigned int u = __float_as_uint(x);
    unsigned int r = (u + 0x7FFFu + ((u >> 16) & 1u)) >> 16;
    return (unsigned short)r;
}

// -------- preds DMA stage: 32 rows (16 i x 2 v) x 128 l = 16 KB ------------
// SEGMENT-HALVING layout: each instr covers 2 rows x 512 B (lane>>5 = row,
// (lane&31)*16B = col) -> 2 HBM segments/instr vs the old 4x256B.  Session
// model (fits R2-R11 within 5%): time = HBM segments/CU x ~38.8 ns;
// all prior variants = 1260 segs/CU = 49 us; this = ~640 -> ~25 us.
static __device__ __forceinline__ void k1_stage(
    const float* __restrict__ preds, float* __restrict__ dst,
    int b, int v0, int l0, int L, int lane, int wave)
{
#pragma unroll
    for (int n = 0; n < 4; ++n) {
        int r0 = wave * 8 + n * 2;                // wave-uniform row pair
        int r = r0 + (lane >> 5);                 // this lane's row (i*2+vc)
        int grow = b * 256 + (r >> 1) * 16 + v0 + (r & 1);
        const float* g = preds + (size_t)grow * L + l0 + (lane & 31) * 4;
        __builtin_amdgcn_global_load_lds(
            (const __attribute__((address_space(1))) unsigned int*)g,
            (__attribute__((address_space(3))) unsigned int*)(dst + r0 * 128),
            16, 0, 0);
    }
}

// -------- target DMA stage (once, prologue): 16 rows x 128 l = 8 KB --------
static __device__ __forceinline__ void k1_stage_t(
    const float* __restrict__ target, float* __restrict__ dst,
    int b, int l0, int L, int lane, int wave)
{
#pragma unroll
    for (int n = 0; n < 2; ++n) {
        int r0 = wave * 4 + n * 2;                // wave-uniform row pair
        int r = r0 + (lane >> 5);                 // v row
        const float* g = target + (size_t)(b * V + r) * L + l0 + (lane & 31) * 4;
        __builtin_amdgcn_global_load_lds(
            (const __attribute__((address_space(1))) unsigned int*)g,
            (__attribute__((address_space(3))) unsigned int*)(dst + r0 * 128),
            16, 0, 0);
    }
}

// -------- per-2v-stage pair/target accumulation (verified math/order) ------
// lcol selects the l-half (lane or 64+lane); y comes from the LDS target
// tile (no per-wave targ registers -> dual-acc fits under 128 VGPR).
template<int W>
static __device__ __forceinline__ void k1_chunk(
    const float* __restrict__ xsb,                // 32 rows x 128 f32
    const float* __restrict__ tl,                 // 16 rows x 128 f32 targets
    const float* __restrict__ scl,                // scale[16]
    float wl, int v0, int lcol, float* __restrict__ acc)
{
    const int base = (W == 0) ? 0 : 34 * W - 16;  // first pair idx
    const int npair = (W == 0) ? 18 : 34;
    const int aoff = (W == 0) ? 16 : 0;

#pragma unroll
    for (int vc = 0; vc < 2; ++vc) {
        const int v = v0 + vc;                    // compile-time after unroll
        float s = scl[v] * wl;
        float x[M];
#pragma unroll
        for (int i = 0; i < M; ++i)
            x[i] = xsb[(i * 2 + vc) * 128 + lcol] * s;
        if (W == 0) {
            float y = tl[v * 128 + lcol] * s;
#pragma unroll
            for (int i = 0; i < M; ++i) {
                float d = x[i] - y;
                acc[i] = fmaf(d, d, acc[i]);
            }
        }
        int k = 0;
#pragma unroll
        for (int i = 0; i < M; ++i) {
#pragma unroll
            for (int j = i + 1; j < M; ++j) {
                if (k >= base && k < base + npair) {
                    float d = x[i] - x[j];
                    acc[aoff + k - base] = fmaf(d, d, acc[aoff + k - base]);
                }
                ++k;
            }
        }
    }
}

// -------- Fused kernel: 512B-segment staged pair-sums + dual MFMA tail -----
// Block (pb,b) owns 128 l's.  R7-proven schedule: 4 x 16 KB buffers, 3-deep
// prefetch, counted vmcnt (4 instrs/stage -> VMW(8)/4/0), raw s_barrier,
// sched_barrier(0) pins (rule 18).  Per stage each wave computes BOTH
// l-halves (accA/accB).  Tail: S-write+MFMA for half A, barrier, half B
// (pacc accumulates across halves -- D2 is linear in l).  LDS = 64K xs +
// 8K tl = 72 KB -> 2 blocks/CU; sld aliases xs[0..] (dead post-loop; s=7
// compute reads xs[3] only, disjoint).  Spill tripwire: WRITE > 11 MB.
__global__ __launch_bounds__(256, 2)
void k1_fused(const float* __restrict__ preds, const float* __restrict__ target,
              const float* __restrict__ weights, const float* __restrict__ scale,
              const float* __restrict__ masks, float* __restrict__ partial,
              float* __restrict__ out, int L)
{
    __shared__ float xs[4][4096];                 // 4 x 16 KB DMA buffers
    __shared__ float tl[16 * 128];                // 8 KB target tile
    unsigned short* sld = (unsigned short*)&xs[0][0];   // 18.4 KB alias (tail)

    const int t = (int)threadIdx.x;
    const int lane = t & 63, wave = t >> 6;
    const int pb = (int)blockIdx.x;
    const int b  = (int)blockIdx.y;
    const int l0 = pb * 128;

    if (pb == 0 && b == 0 && t == 0) out[0] = 0.0f;   // k3b atomics ordered after

    const size_t Ls = (size_t)L;

    // prologue scalars first (no drain; in-order completion keeps loop
    // vmcnt conservative-correct -- v11-verified pattern)
    const float wlA = weights[l0 + lane];
    const float wlB = weights[l0 + 64 + lane];
    float scl[V];
#pragma unroll
    for (int v = 0; v < V; ++v) scl[v] = scale[v];
    __builtin_amdgcn_sched_barrier(0);            // scalars above, DMAs below

    // DMA prologue: targets (2 instrs) + stages 0..2 (12 instrs)
    k1_stage_t(target, tl, b, l0, L, lane, wave);
    k1_stage(preds, &xs[0][0], b, 0, l0, L, lane, wave);
    k1_stage(preds, &xs[1][0], b, 2, l0, L, lane, wave);
    k1_stage(preds, &xs[2][0], b, 4, l0, L, lane, wave);

    float accA[34], accB[34];
#pragma unroll
    for (int r = 0; r < 34; ++r) { accA[r] = 0.0f; accB[r] = 0.0f; }

#pragma unroll
    for (int s = 0; s < 8; ++s) {
        // wait stage s (and, at s=0, the target tile); keep s+1,s+2 in flight
        if (s < 6)      { VMW(8); }
        else if (s == 6){ VMW(4); }
        else            { VMW(0); }
        __builtin_amdgcn_s_barrier();             // all waves: stage s landed
        __builtin_amdgcn_sched_barrier(0);        // pin ds_reads/issues (r18)
        if (s < 5)                                // DMA(s+3) -> buf[(s+3)&3]
            k1_stage(preds, &xs[(s + 3) & 3][0], b, (s + 3) * 2, l0, L, lane, wave);
        const float* xsb = &xs[s & 3][0];
        switch (wave) {
            case 0: k1_chunk<0>(xsb, tl, scl, wlA, s * 2, lane, accA);
                    k1_chunk<0>(xsb, tl, scl, wlB, s * 2, 64 + lane, accB); break;
            case 1: k1_chunk<1>(xsb, tl, scl, wlA, s * 2, lane, accA);
                    k1_chunk<1>(xsb, tl, scl, wlB, s * 2, 64 + lane, accB); break;
            case 2: k1_chunk<2>(xsb, tl, scl, wlA, s * 2, lane, accA);
                    k1_chunk<2>(xsb, tl, scl, wlB, s * 2, 64 + lane, accB); break;
            default: k1_chunk<3>(xsb, tl, scl, wlA, s * 2, lane, accA);
                     k1_chunk<3>(xsb, tl, scl, wlB, s * 2, 64 + lane, accB); break;
        }
    }
    // post top-of-s=7 barrier all waves are past s=6; s=7 compute reads only
    // xs[3] (48-64 KB region) -> writing sld (first 18.4 KB) is safe

    // pad rows 136..143 = 0 (tile 8's upper half; persists across both halves)
    ((unsigned int*)sld)[136 * 32 + t] = 0;

    const int ntile = (wave == 3) ? 3 : 2;        // wave3 also owns tile 8
    f32x4 pacc[3][2];
#pragma unroll
    for (int ti = 0; ti < 3; ++ti)
#pragma unroll
        for (int pt = 0; pt < 2; ++pt)
            pacc[ti][pt] = (f32x4){0.f, 0.f, 0.f, 0.f};

#pragma unroll
    for (int half = 0; half < 2; ++half) {
        const float* acc = (half == 0) ? accA : accB;   // static after unroll
        // ---- acc -> S_lds, XOR-swizzled (row stride 128 B = 16-way conflict
        // on b128 reads; XOR row&7 into bits[3:5] -> residual 2-way = free)
#pragma unroll
        for (int r = 0; r < 34; ++r) {
            const int R = 34 * wave + r;
            sld[R * 64 + (lane ^ ((R & 7) << 3))] = f2bf(acc[r]);
        }
        __syncthreads();                          // cross-wave: tiles mix writers

        // ---- MFMA: pacc += S_tile x mask^T (layouts from verified k2)
#pragma unroll
        for (int ks = 0; ks < 2; ++ks) {
            bf16x8 bfr[2];
#pragma unroll
            for (int pt = 0; pt < 2; ++pt) {
                const float* mp = masks + (size_t)(pt * 16 + (lane & 15)) * Ls
                                + l0 + half * 64 + ks * 32 + (lane >> 4) * 8;
                u32x4 m0 = *(const u32x4*)mp;
                u32x4 m1 = *(const u32x4*)(mp + 4);
                union { unsigned int u[4]; bf16x8 v; } bb;
                bb.u[0] = __builtin_amdgcn_perm(m0.y, m0.x, 0x07060302);
                bb.u[1] = __builtin_amdgcn_perm(m0.w, m0.z, 0x07060302);
                bb.u[2] = __builtin_amdgcn_perm(m1.y, m1.x, 0x07060302);
                bb.u[3] = __builtin_amdgcn_perm(m1.w, m1.z, 0x07060302);
                bfr[pt] = bb.v;
            }
#pragma unroll
            for (int ti = 0; ti < 3; ++ti) {
                if (ti >= ntile) continue;        // wave-uniform
                const int tile = (ti == 2) ? 8 : (wave + ti * 4);
                const bf16x8 a = *(const bf16x8*)&sld[
                    (tile * 16 + (lane & 15)) * 64 +
                    ((ks * 32 + (lane >> 4) * 8) ^ ((lane & 7) << 3))];
                pacc[ti][0] = __builtin_amdgcn_mfma_f32_16x16x32_bf16(
                    a, bfr[0], pacc[ti][0], 0, 0, 0);
                pacc[ti][1] = __builtin_amdgcn_mfma_f32_16x16x32_bf16(
                    a, bfr[1], pacc[ti][1], 0, 0, 0);
            }
        }
        if (half == 0)
            __syncthreads();                      // all A-frag reads done
    }

    // ---- store partial D2 for slot pb, batch b: [136][32] f32 -------------
    float* P = partial + (size_t)pb * PBSTRIDE + (size_t)b * (NROWB * PMASK);
#pragma unroll
    for (int ti = 0; ti < 3; ++ti) {
        if (ti >= ntile) continue;
        const int tile = (ti == 2) ? 8 : (wave + ti * 4);
#pragma unroll
        for (int pt = 0; pt < 2; ++pt)
#pragma unroll
            for (int reg = 0; reg < 4; ++reg) {
                const int row = tile * 16 + (lane >> 4) * 4 + reg;
                if (row < NROWB)                  // drop pad rows 136..143
                    P[row * 32 + pt * 16 + (lane & 15)] = pacc[ti][pt][reg];
            }
    }
}

// -------- k3a: parallel pb-group sum: 34 x 15 blocks, 21 pb each -----------
__global__ __launch_bounds__(256, 2)
void k3a_reduce(const float* __restrict__ P, float* __restrict__ P2)
{
    const int t = (int)threadIdx.x;
    const int e = (int)blockIdx.x * 256 + t;      // 0..8703 = b*4352+row*32+p
    const int spl = (int)blockIdx.y;              // 0..14

    const float* p = P + (size_t)(spl * QPB) * PBSTRIDE + e;
    float a[7];
#pragma unroll
    for (int j = 0; j < 7; ++j) a[j] = 0.f;
    for (int q = 0; q < QPB; q += 7) {            // 21 = 3*7, 7 indep streams
#pragma unroll
        for (int j = 0; j < 7; ++j)
            a[j] += p[(size_t)(q + j) * PBSTRIDE];
    }
    P2[(size_t)spl * NE + e] =
        ((a[0] + a[1]) + (a[2] + a[3])) + ((a[4] + a[5]) + a[6]);
}

// -------- k3b: final 15-sum (L2-resident), sqrt, weighted reduce, atomic ---
__global__ __launch_bounds__(256, 2)
void k3b_finalize(const float* __restrict__ P2, const int* __restrict__ beta_p,
                  float* __restrict__ out)
{
    const int t = (int)threadIdx.x;
    const int e = (int)blockIdx.x * 256 + t;      // 0..8703

    float a0 = 0.f, a1 = 0.f, a2 = 0.f;
#pragma unroll
    for (int q = 0; q < SPLIT; q += 3) {          // 15 independent loads
        a0 += P2[(size_t)(q    ) * NE + e];
        a1 += P2[(size_t)(q + 1) * NE + e];
        a2 += P2[(size_t)(q + 2) * NE + e];
    }
    float d2 = fmaxf((a0 + a1) + a2, 0.0f);
    float beta = (float)beta_p[0];
    float d = (beta == 1.0f) ? sqrtf(d2) : powf(d2, 0.5f * beta);

    const float wa = 1.0f / (float)(BS * M);
    const float wb = -1.0f / (float)(BS * M * (M - 1));
    const int row_g = e >> 5;                     // b*136 + row
    const int local = row_g % NROWB;
    float sum = ((local < M) ? wa : wb) * d;

    const int lane = t & 63, wv = t >> 6;
#pragma unroll
    for (int off = 32; off > 0; off >>= 1)
        sum += __shfl_down(sum, off, 64);
    __shared__ float red[4];
    if (lane == 0) red[wv] = sum;
    __syncthreads();
    if (t == 0)
        atomicAdd(out, red[0] + red[1] + red[2] + red[3]);
}

extern "C" void kernel_launch(void* const* d_in, const int* in_sizes, int n_in,
                              void* d_out, int out_size, void* d_ws, size_t ws_size,
                              hipStream_t stream)
{
    const float* preds   = (const float*)d_in[0];
    const float* target  = (const float*)d_in[1];
    const float* weights = (const float*)d_in[2];
    const float* scale   = (const float*)d_in[3];
    const float* masks   = (const float*)d_in[4];
    const int*   beta    = (const int*)d_in[5];
    float* out = (float*)d_out;

    int L = in_sizes[2];   // 40320 = NPB*128

    float* partial = (float*)d_ws;                // 315*8704 f32 = 11.0 MB
    size_t p_bytes = (size_t)NPB * PBSTRIDE * sizeof(float);
    float* partial2 = (float*)((char*)d_ws + ((p_bytes + 255) & ~(size_t)255));
                                                  // 15*8704 f32 = 522 KB

    dim3 g1(NPB, BS);                             // 315 x 2 = 630 blocks
    k1_fused<<<g1, 256, 0, stream>>>(preds, target, weights, scale, masks,
                                     partial, out, L);

    dim3 g3a(NE / 256, SPLIT);                    // 34 x 15
    k3a_reduce<<<g3a, 256, 0, stream>>>(partial, partial2);

    k3b_finalize<<<NE / 256, 256, 0, stream>>>(partial2, beta, out);
}